// Round 3
// baseline (240.778 us; speedup 1.0000x reference)
//
#include <hip/hip_runtime.h>

// Conditional InstanceNorm2d: x[B=32,C=256,H=64,W=64] fp32, style_id[B] int32,
// gamma/beta[S=16,C=256] fp32 -> out fp32.
//
// Dtype forensics (prior session): all tensors fp32, style_id int32, output
// fp32 (bf16 experiments -> NaN / packed-garbage mismatches).
//
// Session ledger:
//   R0 block-lockstep (LDS reduce):            kernel ~76 us
//   R4 wave-per-instance (remat bug, VGPR 40): kernel 80.7 us, 2.5 TB/s HBM,
//                                              VALUBusy 3.7%, Occ 42%
//   R5 + asm-pin of d[16]:                     kernel ~78 us (total 234.7,
//                                              minus 156.6 us of harness fills)
//   All three ~3.3 TB/s effective while the harness fill does 6.7 TB/s and
//   float4 D2D copy (same read+write mix) does 6.29 TB/s -> not a BW ceiling.
//
// R6 theory: the common defect is the wave lifecycle load-all -> wait-all ->
// reduce -> store -> EXIT: one full HBM-latency burst per 32 KiB, no
// intra-wave overlap, waves die young (R4 math: mean lifetime ~34 us parked
// at vmcnt). Fix = persistent waves + register double-buffer prefetch:
//   - 2048 waves exactly (= device capacity at 2 waves/SIMD for ~160 VGPR,
//     __launch_bounds__(64,2)), 4 instances per wave, fully resident.
//   - While computing stats/stores of instance k, the 16 loads of k+1 are
//     already in flight (issued BEFORE the pin/wait of the current buffer;
//     compiler emits counted vmcnt so the prefetch stays outstanding).
//   - asm "+v" pins at CONSUMPTION time: blocks rematerialization without
//     forcing an early drain of the prefetch.
//   - Non-temporal stores: out (128 MiB) stops thrashing L3 against x
//     (128 MiB) in the 256 MiB Infinity Cache.
// One-pass roofline: 256 MiB at ~6 TB/s ~= 42-45 us kernel.

#define HW    4096
#define NC    256
#define NPER  4            // instances per wave
#define NWAVE 2048         // 8192 / NPER; == 256 CU * 8 waves/CU resident

typedef float vfloat4 __attribute__((ext_vector_type(4)));

__global__ __launch_bounds__(64, 2) void cin2d_kernel(
    const float* __restrict__ x,
    const int* __restrict__ style_id,
    const float* __restrict__ gamma,
    const float* __restrict__ beta,
    float* __restrict__ out)
{
    const int lane  = threadIdx.x;           // 0..63, one wave per block
    const int inst0 = blockIdx.x * NPER;     // this wave owns [inst0, inst0+4)

    const vfloat4* xp = (const vfloat4*)(x   + (size_t)inst0 * HW) + lane;
    vfloat4*       op = (vfloat4*)      (out + (size_t)inst0 * HW) + lane;

    vfloat4 A[16], B[16];

    // Prologue: issue loads for instance 0 into A.
#pragma unroll
    for (int i = 0; i < 16; ++i) A[i] = xp[i * 64];

    // One pipeline stage. CUR was loaded in the previous stage; NXT's loads
    // are issued here, before CUR is consumed, so they fly during the
    // stats/reduce/store of CUR. All indices compile-time static.
    auto STEP = [&](vfloat4 (&CUR)[16], vfloat4 (&NXT)[16], int k,
                    bool prefetch) {
        if (prefetch) {
            const vfloat4* xn = xp + (size_t)(k + 1) * (HW / 4);
#pragma unroll
            for (int i = 0; i < 16; ++i) NXT[i] = xn[i * 64];
        }

        // Style params for this instance (uniform per wave -> scalar loads);
        // issued before the stats chain so their latency overlaps it.
        const int inst = inst0 + k;
        const int b = inst >> 8;
        const int c = inst & (NC - 1);
        const int sid = style_id[b];
        const float g  = gamma[sid * NC + c];
        const float be = beta[sid * NC + c];

        // Pin CUR at consumption: forces the wait for CUR's 16 loads only
        // (NXT's 16 newer loads stay outstanding) and forbids remat.
#pragma unroll
        for (int i = 0; i < 16; ++i) asm volatile("" : "+v"(CUR[i]));

        // 4 independent accumulator chains.
        float s0 = 0.f, s1 = 0.f, s2 = 0.f, s3 = 0.f;
        float q0 = 0.f, q1 = 0.f, q2 = 0.f, q3 = 0.f;
#pragma unroll
        for (int i = 0; i < 16; ++i) {
            s0 += CUR[i][0];  q0 = fmaf(CUR[i][0], CUR[i][0], q0);
            s1 += CUR[i][1];  q1 = fmaf(CUR[i][1], CUR[i][1], q1);
            s2 += CUR[i][2];  q2 = fmaf(CUR[i][2], CUR[i][2], q2);
            s3 += CUR[i][3];  q3 = fmaf(CUR[i][3], CUR[i][3], q3);
        }
        float s = (s0 + s1) + (s2 + s3);
        float q = (q0 + q1) + (q2 + q3);

        // Wave-wide butterfly: 6 steps, all 64 lanes end with totals.
#pragma unroll
        for (int off = 1; off < 64; off <<= 1) {
            s += __shfl_xor(s, off, 64);
            q += __shfl_xor(q, off, 64);
        }

        const float inv_n = 1.0f / (float)HW;
        const float mean = s * inv_n;
        float var = fmaf(-mean, mean, q * inv_n);   // biased variance
        var = var < 0.0f ? 0.0f : var;
        const float rstd = rsqrtf(var + 1e-5f);

        const float scale = g * rstd;
        const float shift = fmaf(-mean, scale, be);

        vfloat4* o = op + (size_t)k * (HW / 4);
#pragma unroll
        for (int i = 0; i < 16; ++i) {
            vfloat4 w;
#pragma unroll
            for (int j = 0; j < 4; ++j) w[j] = fmaf(CUR[i][j], scale, shift);
            __builtin_nontemporal_store(w, &o[i * 64]);
        }
    };

    STEP(A, B, 0, true);
    STEP(B, A, 1, true);
    STEP(A, B, 2, true);
    STEP(B, A, 3, false);
}

extern "C" void kernel_launch(void* const* d_in, const int* in_sizes, int n_in,
                              void* d_out, int out_size, void* d_ws, size_t ws_size,
                              hipStream_t stream) {
    const float* x     = (const float*)d_in[0];
    const int*   sid   = (const int*)d_in[1];
    const float* gamma = (const float*)d_in[2];
    const float* beta  = (const float*)d_in[3];
    float* out = (float*)d_out;

    dim3 grid(NWAVE), block(64);   // persistent: one full-device residency
    hipLaunchKernelGGL(cin2d_kernel, grid, block, 0, stream,
                       x, sid, gamma, beta, out);
}

// Round 5
// 228.770 us; speedup vs baseline: 1.0525x; 1.0525x over previous
//
#include <hip/hip_runtime.h>

// Conditional InstanceNorm2d: x[B=32,C=256,H=64,W=64] fp32, style_id[B] int32,
// gamma/beta[S=16,C=256] fp32 -> out fp32.
//
// Dtype forensics (prior session): all tensors fp32, style_id int32, output
// fp32 (bf16 experiments -> NaN / packed-garbage mismatches).
//
// Session ledger (kernel time = total dur_us minus ~157 us of harness poison
// fills, cross-checked against rocprof dispatch rows where captured):
//   R0 block-lockstep 256thr (LDS reduce):      ~76 us
//   R4 wave-per-instance 64thr (remat bug):     80.7 us | 2.5 TB/s, Occ 42%
//   R5 + asm-pin:                               ~78 us
//   R6 persistent 2048-wave double-buffer + NT STORES:
//                                               84.3 us | 2.4 TB/s, Occ 17%,
//                                               VGPR 100, VALUBusy 3.2%
//   R7 (this kernel): DID NOT RUN -- broker container failure, resubmitting.
// All structures plateau at 3.2-3.5 TB/s effective while the harness fill
// does 6.7 TB/s write-only. Latency/occupancy/instruction overhead are all
// ruled out (one wave's 16 KB outstanding > 10.6 KB/CU needed; VALUBusy 3%).
//
// R7 theory: L3 contention between streams. x (128 MiB, read ONCE) evicts
// out's lines from the 256 MiB Infinity Cache, so the write stream drains to
// HBM synchronously and reads miss (FETCH showed only half of x L3-hit).
// R6's NT *stores* (anti-retain the writes) regressed -- so flip the hint:
//   - NT LOADS for x (evict-first: zero L3 residency for the read-once data)
//   - normal cached stores (L3 free to absorb the whole 128 MiB out stream)
// Geometry reverts to the best known: 256-thr blocks, 4 independent waves,
// one instance per wave, no LDS/barriers, one-shot, asm-pin vs remat.
// Predict kernel ~55-65 us (total ~212-222) and FETCH rising toward 128 MiB;
// if flat, the mixed-stream plateau is structural -> two-pass next.

#define HW   4096
#define NC   256
#define NTHR 256

typedef float vfloat4 __attribute__((ext_vector_type(4)));

__global__ __launch_bounds__(NTHR) void cin2d_kernel(
    const float* __restrict__ x,
    const int* __restrict__ style_id,
    const float* __restrict__ gamma,
    const float* __restrict__ beta,
    float* __restrict__ out)
{
    const int wave = threadIdx.x >> 6;
    const int lane = threadIdx.x & 63;
    const int inst = (blockIdx.x << 2) + wave;   // inst = b*NC + c
    const int b = inst >> 8;
    const int c = inst & (NC - 1);

    // 16 KiB instance, 64 lanes x 16 float4: each wave-instruction is one
    // fully-coalesced 1 KiB segment, sequential across i.
    const vfloat4* xp = (const vfloat4*)(x + (size_t)inst * HW) + lane;

    vfloat4 d[16];
#pragma unroll
    for (int i = 0; i < 16; ++i) d[i] = __builtin_nontemporal_load(xp + i * 64);

    // Pin the tile in VGPRs: forbids rematerialization of the loads in the
    // store phase (R4 bug: compiler legally re-read x, doubling traffic --
    // with NT loads a remat would be a guaranteed HBM re-read).
#pragma unroll
    for (int i = 0; i < 16; ++i) asm volatile("" : "+v"(d[i]));

    // Style-indexed affine params (tiny, reused across blocks -> cached).
    const int sid = style_id[b];
    const float g  = gamma[sid * NC + c];
    const float be = beta[sid * NC + c];

    // 4 independent accumulator chains.
    float s0 = 0.f, s1 = 0.f, s2 = 0.f, s3 = 0.f;
    float q0 = 0.f, q1 = 0.f, q2 = 0.f, q3 = 0.f;
#pragma unroll
    for (int i = 0; i < 16; ++i) {
        s0 += d[i][0];  q0 = fmaf(d[i][0], d[i][0], q0);
        s1 += d[i][1];  q1 = fmaf(d[i][1], d[i][1], q1);
        s2 += d[i][2];  q2 = fmaf(d[i][2], d[i][2], q2);
        s3 += d[i][3];  q3 = fmaf(d[i][3], d[i][3], q3);
    }
    float s = (s0 + s1) + (s2 + s3);
    float q = (q0 + q1) + (q2 + q3);

    // Wave-wide butterfly: 6 steps, all 64 lanes end with the totals.
    // No LDS, no barrier, the block's 4 waves stay fully decoupled.
#pragma unroll
    for (int off = 1; off < 64; off <<= 1) {
        s += __shfl_xor(s, off, 64);
        q += __shfl_xor(q, off, 64);
    }

    const float inv_n = 1.0f / (float)HW;
    const float mean = s * inv_n;
    float var = fmaf(-mean, mean, q * inv_n);   // E[x^2] - mean^2 (biased)
    var = var < 0.0f ? 0.0f : var;
    const float rstd = rsqrtf(var + 1e-5f);

    const float scale = g * rstd;
    const float shift = fmaf(-mean, scale, be);

    // Normal cached stores: let the 256 MiB L3 absorb the write stream
    // (now unpolluted by x, which was loaded evict-first).
    vfloat4* op = (vfloat4*)(out + (size_t)inst * HW) + lane;
#pragma unroll
    for (int i = 0; i < 16; ++i) {
        vfloat4 w;
#pragma unroll
        for (int j = 0; j < 4; ++j) w[j] = fmaf(d[i][j], scale, shift);
        op[i * 64] = w;
    }
}

extern "C" void kernel_launch(void* const* d_in, const int* in_sizes, int n_in,
                              void* d_out, int out_size, void* d_ws, size_t ws_size,
                              hipStream_t stream) {
    const float* x     = (const float*)d_in[0];
    const int*   sid   = (const int*)d_in[1];
    const float* gamma = (const float*)d_in[2];
    const float* beta  = (const float*)d_in[3];
    float* out = (float*)d_out;

    const int B = 32, C = 256;
    dim3 grid((B * C) / 4), block(NTHR);   // 4 waves/block, 1 instance/wave
    hipLaunchKernelGGL(cin2d_kernel, grid, block, 0, stream,
                       x, sid, gamma, beta, out);
}